// Round 1
// baseline (249.670 us; speedup 1.0000x reference)
//
#include <hip/hip_runtime.h>
#include <cmath>
#include <cstdint>

// B=64, T=64, W=20, D=1024, K=4, STRIDE=4 ; conv lengths 64->16->4->1 ; T_total=21
// VCb is STACKED: rows [0,1024)=conv0-level (j=r>>4,t=r&15), [1024,1280)=conv1-level
// (j=(r-1024)>>2, t=16+((r-1024)&3)), [1280,1344)=conv2-level (j=r-1280, t=20).

typedef __bf16 bf16_t;
typedef bf16_t bf16x8 __attribute__((ext_vector_type(8)));
typedef bf16_t bf16x4 __attribute__((ext_vector_type(4)));
typedef float  f32x4  __attribute__((ext_vector_type(4)));

#define CP0_SL   1048576
#define CP1_SL   262144
#define CPC0_SL  1048576
#define CP2_SL   65536
#define CPC1_SL  262144
#define CPC2_SL  65536
#define CPFC_SL  65536
#define CPAT_SL  1720320

#define MFMA16(a,b,c) __builtin_amdgcn_mfma_f32_16x16x32_bf16(a, b, c, 0, 0, 0)

__device__ __forceinline__ void gload_lds16(const void* g, void* l) {
    __builtin_amdgcn_global_load_lds(
        (const __attribute__((address_space(1))) void*)g,
        (__attribute__((address_space(3))) void*)l, 16, 0, 0);
}

// swizzled LDS offset (bf16 units): physical chunk = c ^ (row&7). row stride 64 bf16.
__device__ __forceinline__ int swz(int r, int c) { return (r * 8 + (c ^ (r & 7))) * 8; }

// ---------------- shared 64x64 bf16 MFMA NT tile (double-buffered) ------------
__device__ __forceinline__ void gemm64(
    const bf16_t* __restrict__ A, const bf16_t* __restrict__ B,
    float* __restrict__ Cz, int Nc, int K,
    int m0A, int n0B, int k0, int nIt, int m0C, int n0C,
    bf16_t* sA, bf16_t* sB)                 // each 2*4096 bf16
{
    const int tid  = threadIdx.x;
    const int lane = tid & 63, wave = tid >> 6;
    const int sr = tid >> 3, pc = tid & 7, lc = pc ^ (sr & 7);
    const bf16_t* Ag = A + (size_t)(m0A + sr) * K + k0 + lc * 8;
    const bf16_t* Bg = B + (size_t)(n0B + sr) * K + k0 + lc * 8;
    const size_t rowskip = (size_t)32 * K;
    const int wr = (wave >> 1) * 32, wc = (wave & 1) * 32;
    const int fm = lane & 15, cb = lane >> 4;
    int offA[2][2], offB[2][2];
    #pragma unroll
    for (int h = 0; h < 2; h++) {
        offA[h][0] = swz(wr +      fm, cb + h * 4);
        offA[h][1] = swz(wr + 16 + fm, cb + h * 4);
        offB[h][0] = swz(wc +      fm, cb + h * 4);
        offB[h][1] = swz(wc + 16 + fm, cb + h * 4);
    }
    f32x4 acc[2][2];
    #pragma unroll
    for (int a = 0; a < 2; a++)
        #pragma unroll
        for (int b = 0; b < 2; b++) acc[a][b] = (f32x4){0.f, 0.f, 0.f, 0.f};

    gload_lds16(Ag,           sA + tid * 8);
    gload_lds16(Ag + rowskip, sA + 2048 + tid * 8);
    gload_lds16(Bg,           sB + tid * 8);
    gload_lds16(Bg + rowskip, sB + 2048 + tid * 8);
    for (int it = 0; it < nIt; ++it) {
        const int buf = it & 1;
        const bf16_t* cA = sA + buf * 4096;
        const bf16_t* cB = sB + buf * 4096;
        __syncthreads();
        if (it + 1 < nIt) {
            const bf16_t* a = Ag + (it + 1) * 64;
            const bf16_t* b = Bg + (it + 1) * 64;
            bf16_t* dA = sA + (buf ^ 1) * 4096;
            bf16_t* dB = sB + (buf ^ 1) * 4096;
            gload_lds16(a,           dA + tid * 8);
            gload_lds16(a + rowskip, dA + 2048 + tid * 8);
            gload_lds16(b,           dB + tid * 8);
            gload_lds16(b + rowskip, dB + 2048 + tid * 8);
        }
        #pragma unroll
        for (int h = 0; h < 2; h++) {
            bf16x8 a0 = *(const bf16x8*)&cA[offA[h][0]];
            bf16x8 a1 = *(const bf16x8*)&cA[offA[h][1]];
            bf16x8 b0 = *(const bf16x8*)&cB[offB[h][0]];
            bf16x8 b1 = *(const bf16x8*)&cB[offB[h][1]];
            acc[0][0] = MFMA16(a0, b0, acc[0][0]);
            acc[0][1] = MFMA16(a0, b1, acc[0][1]);
            acc[1][0] = MFMA16(a1, b0, acc[1][0]);
            acc[1][1] = MFMA16(a1, b1, acc[1][1]);
        }
    }
    // C/D layout: col = lane&15, row = (lane>>4)*4 + reg   [verified m89/m91]
    #pragma unroll
    for (int im = 0; im < 2; im++)
        #pragma unroll
        for (int rr = 0; rr < 4; rr++) {
            int gm = m0C + wr + im * 16 + cb * 4 + rr;
            #pragma unroll
            for (int in_ = 0; in_ < 2; in_++) {
                int cg = n0C + wc + in_ * 16 + fm;
                Cz[(size_t)gm * Nc + cg] = acc[im][in_][rr];
            }
        }
}

// ---------------- wave-per-row L2 norm of a VCb row ---------------------------
__device__ __forceinline__ void rownorm_row(const bf16_t* __restrict__ VCb,
                                            float* __restrict__ VN, int r, int tid)
{
    const int lane = tid & 63;
    const bf16_t* x = VCb + ((size_t)r << 10) + lane * 16;
    bf16x8 v0 = *(const bf16x8*)x, v1 = *(const bf16x8*)(x + 8);
    float s = 0.f;
    #pragma unroll
    for (int e = 0; e < 8; e++) {
        float a = (float)v0[e], b = (float)v1[e];
        s += a * a + b * b;
    }
    #pragma unroll
    for (int o = 32; o; o >>= 1) s += __shfl_xor(s, o, 64);
    if (lane == 0) VN[r] = sqrtf(s);
}

// ---------------- per-(i, stacked-col) sim (Gs/msk pre-staged + synced) -------
__device__ __forceinline__ void sim_compute(
    int i, int c, const float* __restrict__ CPat, const float* __restrict__ VN,
    const float* Gs, const float* msk, float* __restrict__ SA)
{
    float s[20], p[20];
    float mx = -1e30f;
    #pragma unroll
    for (int w = 0; w < 20; w++) {
        size_t q = (size_t)(i * 20 + w) * 1344 + c;
        s[w] = CPat[q] + CPat[q + CPAT_SL];
        if (msk[w] != 0.f) mx = fmaxf(mx, s[w]);
    }
    float denom = 0.f, num = 0.f;
    #pragma unroll
    for (int w = 0; w < 20; w++) {
        p[w] = (msk[w] != 0.f) ? __expf(s[w] - mx) : 0.f;
        denom += p[w];
        num   += p[w] * s[w];
    }
    float quad = 0.f;
    #pragma unroll
    for (int w = 0; w < 20; w++) {
        float cc = 0.f;
        #pragma unroll
        for (int w2 = 0; w2 < 20; w2++) cc += Gs[w * 20 + w2] * p[w2];
        quad += p[w] * cc;
    }
    float dot = num / denom;
    float vsn = sqrtf(fmaxf(quad, 0.f)) / denom;
    float sim = dot / (fmaxf(VN[c], 1e-8f) * fmaxf(vsn, 1e-8f));
    int j, t;
    if (c < 1024)      { j = c >> 4;          t = c & 15; }
    else if (c < 1280) { j = (c - 1024) >> 2; t = 16 + ((c - 1024) & 3); }
    else               { j = c - 1280;        t = 20; }
    SA[((size_t)i * 64 + j) * 21 + t] = sim;
}

// ================= D1: WT0 transpose + video cast (gates conv0) ===============
__global__ __launch_bounds__(256) void prep0_kernel(
    const float* __restrict__ c0w, bf16_t* __restrict__ WT0,
    const float* __restrict__ video, bf16_t* __restrict__ Vb)
{
    int bx = blockIdx.x;
    if (bx < 4096) {                       // wt[o][k*1024+i] = w[o][i*4+k]
        int idx = bx * 256 + threadIdx.x;
        int i = idx & 1023, o = idx >> 10;
        float4 v = *(const float4*)(c0w + ((size_t)o << 12) + (i << 2));
        bf16_t* base = WT0 + ((size_t)o << 12) + i;
        base[0]    = (bf16_t)v.x;
        base[1024] = (bf16_t)v.y;
        base[2048] = (bf16_t)v.z;
        base[3072] = (bf16_t)v.w;
    } else {
        int off = ((bx - 4096) * 256 + threadIdx.x) * 4;
        float4 v = *(const float4*)(video + off);
        bf16x4 o4 = { (bf16_t)v.x, (bf16_t)v.y, (bf16_t)v.z, (bf16_t)v.w };
        *(bf16x4*)(Vb + off) = o4;
    }
}

// ========== D2: conv0 128x128 MFMA GEMM (splitK x8)  ||  rest of prep =========
__global__ __launch_bounds__(256) void d2_kernel(
    const bf16_t* __restrict__ Vb, const bf16_t* __restrict__ WT0, float* __restrict__ CP0,
    const float* __restrict__ c1w, const float* __restrict__ c2w,
    bf16_t* __restrict__ WT1, bf16_t* __restrict__ WT2,
    const float* __restrict__ words, bf16_t* __restrict__ Wordsb,
    const float* __restrict__ c1dw, bf16_t* __restrict__ C1b,
    const float* __restrict__ fcw, bf16_t* __restrict__ Fb)
{
    __shared__ __align__(16) bf16_t sA[2][8192];
    __shared__ __align__(16) bf16_t sB[2][8192];
    const int bx = blockIdx.x, tid = threadIdx.x;
    if (bx < 512) {
        // 128x128 tile, 4 waves of 64x64, BK=64, dbuf, m97-structure
        const int z = bx >> 6, rem = bx & 63, xt = rem & 7, yt = rem >> 3;
        const int m0 = xt * 128, n0 = yt * 128, k0 = z * 512;
        const int lane = tid & 63, wave = tid >> 6;
        const int sr = tid >> 3, pc = tid & 7, lc = pc ^ (sr & 7);
        const bf16_t* Ag = Vb  + (size_t)(m0 + sr) * 4096 + k0 + lc * 8;
        const bf16_t* Bg = WT0 + (size_t)(n0 + sr) * 4096 + k0 + lc * 8;
        const size_t rowskip = (size_t)32 * 4096;
        const int wrow = (wave >> 1) * 64, wcol = (wave & 1) * 64;
        const int fm = lane & 15, cb = lane >> 4;
        int offA[2][4], offB[2][4];
        #pragma unroll
        for (int h = 0; h < 2; h++)
            #pragma unroll
            for (int m = 0; m < 4; m++) {
                offA[h][m] = swz(wrow + m * 16 + fm, cb + h * 4);
                offB[h][m] = swz(wcol + m * 16 + fm, cb + h * 4);
            }
        f32x4 acc[4][4];
        #pragma unroll
        for (int m = 0; m < 4; m++)
            #pragma unroll
            for (int n = 0; n < 4; n++) acc[m][n] = (f32x4){0.f, 0.f, 0.f, 0.f};

        #pragma unroll
        for (int g = 0; g < 4; g++) {
            gload_lds16(Ag + g * rowskip, &sA[0][tid * 8 + g * 2048]);
            gload_lds16(Bg + g * rowskip, &sB[0][tid * 8 + g * 2048]);
        }
        for (int it = 0; it < 8; ++it) {
            const int buf = it & 1;
            __syncthreads();
            if (it < 7) {
                const bf16_t* a = Ag + (it + 1) * 64;
                const bf16_t* b = Bg + (it + 1) * 64;
                #pragma unroll
                for (int g = 0; g < 4; g++) {
                    gload_lds16(a + g * rowskip, &sA[buf ^ 1][tid * 8 + g * 2048]);
                    gload_lds16(b + g * rowskip, &sB[buf ^ 1][tid * 8 + g * 2048]);
                }
            }
            #pragma unroll
            for (int h = 0; h < 2; h++) {
                bf16x8 av[4], bv[4];
                #pragma unroll
                for (int m = 0; m < 4; m++) {
                    av[m] = *(const bf16x8*)&sA[buf][offA[h][m]];
                    bv[m] = *(const bf16x8*)&sB[buf][offB[h][m]];
                }
                #pragma unroll
                for (int m = 0; m < 4; m++)
                    #pragma unroll
                    for (int n = 0; n < 4; n++)
                        acc[m][n] = MFMA16(av[m], bv[n], acc[m][n]);
            }
        }
        float* Cz = CP0 + (size_t)z * CP0_SL;
        #pragma unroll
        for (int m = 0; m < 4; m++)
            #pragma unroll
            for (int rr = 0; rr < 4; rr++) {
                int gm = m0 + wrow + m * 16 + cb * 4 + rr;
                #pragma unroll
                for (int n = 0; n < 4; n++) {
                    int cg = n0 + wcol + n * 16 + fm;
                    Cz[(size_t)gm * 1024 + cg] = acc[m][n][rr];
                }
            }
    } else if (bx < 8704) {                 // WT1/WT2 transposes
        const float* w; bf16_t* wt; int b2 = bx - 512;
        if (b2 < 4096) { w = c1w; wt = WT1; }
        else           { w = c2w; wt = WT2; b2 -= 4096; }
        int idx = b2 * 256 + tid;
        int i = idx & 1023, o = idx >> 10;
        float4 v = *(const float4*)(w + ((size_t)o << 12) + (i << 2));
        bf16_t* base = wt + ((size_t)o << 12) + i;
        base[0]    = (bf16_t)v.x;
        base[1024] = (bf16_t)v.y;
        base[2048] = (bf16_t)v.z;
        base[3072] = (bf16_t)v.w;
    } else {                                // words / conv1d_w / fc_w casts
        const float* s; bf16_t* d; int b2 = bx - 8704;
        if (b2 < 1280)      { s = words; d = Wordsb; }
        else if (b2 < 2304) { s = c1dw;  d = C1b; b2 -= 1280; }
        else                { s = fcw;   d = Fb;  b2 -= 2304; }
        int off = (b2 * 256 + tid) * 4;
        float4 v = *(const float4*)(s + off);
        bf16x4 o4 = { (bf16_t)v.x, (bf16_t)v.y, (bf16_t)v.z, (bf16_t)v.w };
        *(bf16x4*)(d + off) = o4;
    }
}

// ============== D3: conv0 epilogue (8 slices, relu)  ||  word gram ============
__global__ __launch_bounds__(256) void d3_kernel(
    const float* __restrict__ CP0, const float* __restrict__ c0b,
    bf16_t* __restrict__ Astack, const bf16_t* __restrict__ Wordsb,
    float* __restrict__ GR)
{
    int bx = blockIdx.x;
    if (bx < 4096) {
        int idx = bx * 256 + threadIdx.x;   // < 1048576
        int n = idx & 1023;
        float s = c0b[n];
        #pragma unroll
        for (int z = 0; z < 8; z++) s += CP0[(size_t)z * CP0_SL + idx];
        Astack[idx] = (bf16_t)fmaxf(s, 0.f);
    } else {
        int g = bx - 4096;                  // 0..6399
        int i = g / 100, piece = g % 100;
        int wave = threadIdx.x >> 6, lane = threadIdx.x & 63;
        int pair = piece * 4 + wave;        // 0..399 = w*20+w2
        int w = pair / 20, w2 = pair % 20;
        const bf16_t* a = Wordsb + (((size_t)i * 20 + w)  << 10) + lane * 16;
        const bf16_t* b = Wordsb + (((size_t)i * 20 + w2) << 10) + lane * 16;
        bf16x8 a0 = *(const bf16x8*)a, a1 = *(const bf16x8*)(a + 8);
        bf16x8 b0 = *(const bf16x8*)b, b1 = *(const bf16x8*)(b + 8);
        float s = 0.f;
        #pragma unroll
        for (int e = 0; e < 8; e++)
            s += (float)a0[e] * (float)b0[e] + (float)a1[e] * (float)b1[e];
        #pragma unroll
        for (int o = 32; o; o >>= 1) s += __shfl_xor(s, o, 64);
        if (lane == 0) GR[(size_t)i * 400 + pair] = s;
    }
}

// ================= D4: conv1 GEMM (x8)  ||  conv1d on conv0 rows (x2) =========
__global__ __launch_bounds__(256) void d4_kernel(
    const bf16_t* __restrict__ Astack, const bf16_t* __restrict__ WT1,
    const bf16_t* __restrict__ C1b, float* __restrict__ CP1, float* __restrict__ CPc0)
{
    __shared__ __align__(16) bf16_t smem[16384];
    bf16_t* sA = smem; bf16_t* sB = smem + 8192;
    int bx = blockIdx.x;
    if (bx < 512) {          // conv1: M=256 N=1024 K=4096
        int z = bx >> 6, rem = bx & 63, xt = rem & 3, yt = rem >> 2;
        gemm64(Astack, WT1, CP1 + (size_t)z * CP1_SL, 1024, 4096,
               xt * 64, yt * 64, z * 512, 8, xt * 64, yt * 64, sA, sB);
    } else {                 // c1d0: M=1024 N=1024 K=1024
        int b2 = bx - 512;
        int z = b2 >> 8, rem = b2 & 255, xt = rem & 15, yt = rem >> 4;
        gemm64(Astack, C1b, CPc0 + (size_t)z * CPC0_SL, 1024, 1024,
               xt * 64, yt * 64, z * 512, 8, xt * 64, yt * 64, sA, sB);
    }
}

// ========= D5: conv1 epi (relu -> A2b)  ||  c1d0 epi (-> VCb rows 0..1023) ====
__global__ __launch_bounds__(256) void d5_kernel(
    const float* __restrict__ CP1, const float* __restrict__ c1b, bf16_t* __restrict__ A2b,
    const float* __restrict__ CPc0, const float* __restrict__ c1db, bf16_t* __restrict__ VCb)
{
    int bx = blockIdx.x;
    if (bx < 1024) {
        int idx = bx * 256 + threadIdx.x;   // < 262144
        int n = idx & 1023;
        float s = c1b[n];
        #pragma unroll
        for (int z = 0; z < 8; z++) s += CP1[(size_t)z * CP1_SL + idx];
        A2b[idx] = (bf16_t)fmaxf(s, 0.f);
    } else {
        int idx = (bx - 1024) * 256 + threadIdx.x;  // < 1048576
        int n = idx & 1023;
        float s = CPc0[idx] + CPc0[idx + CPC0_SL] + c1db[n];
        VCb[idx] = (bf16_t)s;               // stacked rows 0..1023 (identity)
    }
}

// ====== D6: conv2 (x8) || c1d1 (x2) || attn cols 0..1023 (x2) || rownorm0 =====
__global__ __launch_bounds__(256) void d6_kernel(
    const bf16_t* __restrict__ A2b, const bf16_t* __restrict__ WT2,
    const bf16_t* __restrict__ C1b, const bf16_t* __restrict__ Wordsb,
    const bf16_t* __restrict__ VCb, float* __restrict__ CP2,
    float* __restrict__ CPc1, float* __restrict__ CPat, float* __restrict__ VN)
{
    __shared__ __align__(16) bf16_t smem[16384];
    bf16_t* sA = smem; bf16_t* sB = smem + 8192;
    int bx = blockIdx.x;
    if (bx < 128) {          // conv2: M=64 N=1024 K=4096
        int z = bx >> 4, yt = bx & 15;
        gemm64(A2b, WT2, CP2 + (size_t)z * CP2_SL, 1024, 4096,
               0, yt * 64, z * 512, 8, 0, yt * 64, sA, sB);
    } else if (bx < 256) {   // c1d1: M=256 N=1024 K=1024
        int g = bx - 128;
        int z = g >> 6, rem = g & 63, xt = rem & 3, yt = rem >> 2;
        gemm64(A2b, C1b, CPc1 + (size_t)z * CPC1_SL, 1024, 1024,
               xt * 64, yt * 64, z * 512, 8, xt * 64, yt * 64, sA, sB);
    } else if (bx < 896) {   // attn0: M=1280, cols 0..1023, K=1024
        int g = bx - 256;                   // 0..639
        int z = g / 320, rem = g % 320;
        int xt = rem % 20, yt = rem / 20;
        gemm64(Wordsb, VCb, CPat + (size_t)z * CPAT_SL, 1344, 1024,
               xt * 64, yt * 64, z * 512, 8, xt * 64, yt * 64, sA, sB);
    } else {                 // rownorm rows 0..1023
        int r = (bx - 896) * 4 + (threadIdx.x >> 6);
        rownorm_row(VCb, VN, r, threadIdx.x);
    }
}

// == D7: c1d2+fc GEMM w/ FUSED conv2-epilogue A || c1d1 epi || sim cols<1024 ===
__global__ __launch_bounds__(256) void d7_kernel(
    const float* __restrict__ CP2, const float* __restrict__ c2b,
    const bf16_t* __restrict__ C1b, const bf16_t* __restrict__ Fb,
    float* __restrict__ CPc2, float* __restrict__ CPfc,
    const float* __restrict__ CPc1, const float* __restrict__ c1db,
    bf16_t* __restrict__ VCb, const float* __restrict__ CPat,
    const float* __restrict__ GR, const float* __restrict__ VN,
    const int* __restrict__ wmask, float* __restrict__ SA)
{
    __shared__ __align__(16) bf16_t smem[24576];   // 48KB
    const int bx = blockIdx.x, tid = threadIdx.x;
    if (bx < 128) {
        // A = relu(sum_z CP2 + conv2_b), staged once into 64x256 swizzled LDS.
        bf16_t* Abig = smem;                 // 16384 bf16
        bf16_t* sB   = smem + 16384;         // 2 x 4096
        const int which = bx >> 6, rem = bx & 63;
        const int z = rem >> 4, yt = rem & 15;
        const int n0 = yt * 64, k0 = z * 256;
        const bf16_t* Bmat = which ? Fb : C1b;
        float* Cz = (which ? CPfc : CPc2) + (size_t)z * 65536;
        #pragma unroll
        for (int qq = 0; qq < 8; qq++) {
            int q = qq * 256 + tid;          // 0..2047 ; 64 rows x 32 chunks
            int r = q >> 5, ch = q & 31;
            int col = k0 + ch * 8;
            f32x4 s0 = *(const f32x4*)(c2b + col);
            f32x4 s1 = *(const f32x4*)(c2b + col + 4);
            #pragma unroll
            for (int zz = 0; zz < 8; zz++) {
                const float* p = CP2 + (size_t)zz * CP2_SL + r * 1024 + col;
                s0 += *(const f32x4*)p;
                s1 += *(const f32x4*)(p + 4);
            }
            bf16x8 o;
            #pragma unroll
            for (int e = 0; e < 4; e++) {
                o[e]     = (bf16_t)fmaxf(s0[e], 0.f);
                o[4 + e] = (bf16_t)fmaxf(s1[e], 0.f);
            }
            *(bf16x8*)(Abig + r * 256 + ((ch ^ (r & 7)) << 3)) = o;
        }
        // B dbuf loop (K=256 chunk, nIt=4)
        const int lane = tid & 63, wave = tid >> 6;
        const int sr = tid >> 3, pc = tid & 7, lcx = pc ^ (sr & 7);
        const bf16_t* Bg = Bmat + (size_t)(n0 + sr) * 1024 + k0 + lcx * 8;
        const size_t rowskip = (size_t)32 * 1024;
        const int wr = (wave >> 1) * 32, wc = (wave & 1) * 32;
        const int fm = lane & 15, cb = lane >> 4;
        int aoff[2][2], offB[2][2];
        #pragma unroll
        for (int h = 0; h < 2; h++) {
            int r0 = wr + fm, r1 = wr + 16 + fm;
            aoff[h][0] = r0 * 256 + (((cb + 4 * h) ^ (r0 & 7)) << 3);
            aoff[h][1] = r1 * 256 + (((cb + 4 * h) ^ (r1 & 7)) << 3);
            offB[h][0] = swz(wc +      fm, cb + h * 4);
            offB[h][1] = swz(wc + 16 + fm, cb + h * 4);
        }
        f32x4 acc[2][2];
        #pragma unroll
        for (int a = 0; a < 2; a++)
            #pragma unroll
            for (int b = 0; b < 2; b++) acc[a][b] = (f32x4){0.f, 0.f, 0.f, 0.f};
        gload_lds16(Bg,           sB + tid * 8);
        gload_lds16(Bg + rowskip, sB + 2048 + tid * 8);
        for (int it = 0; it < 4; ++it) {
            const int buf = it & 1;
            const bf16_t* cB = sB + buf * 4096;
            __syncthreads();
            if (it < 3) {
                const bf16_t* b = Bg + (it + 1) * 64;
                bf16_t* dB = sB + (buf ^ 1) * 4096;
                gload_lds16(b,           dB + tid * 8);
                gload_lds16(b + rowskip, dB + 2048 + tid * 8);
            }
            #pragma unroll
            for (int h = 0; h < 2; h++) {
                bf16x8 a0 = *(const bf16x8*)&Abig[aoff[h][0] + it * 64];
                bf16x8 a1 = *(const bf16x8*)&Abig[aoff[h][1] + it * 64];
                bf16x8 b0 = *(const bf16x8*)&cB[offB[h][0]];
                bf16x8 b1 = *(const bf16x8*)&cB[offB[h][1]];
                acc[0][0] = MFMA16(a0, b0, acc[0][0]);
                acc[0][1] = MFMA16(a0, b1, acc[0][1]);
                acc[1][0] = MFMA16(a1, b0, acc[1][0]);
                acc[1][1] = MFMA16(a1, b1, acc[1][1]);
            }
        }
        #pragma unroll
        for (int im = 0; im < 2; im++)
            #pragma unroll
            for (int rr = 0; rr < 4; rr++) {
                int gm = wr + im * 16 + cb * 4 + rr;
                #pragma unroll
                for (int in_ = 0; in_ < 2; in_++) {
                    int cg = n0 + wc + in_ * 16 + fm;
                    Cz[(size_t)gm * 1024 + cg] = acc[im][in_][rr];
                }
            }
    } else if (bx < 1152) {  // c1d1 epi -> VCb rows 1024..1279
        int idx = (bx - 128) * 256 + tid;   // < 262144
        int n = idx & 1023;
        float s = CPc1[idx] + CPc1[idx + CPC1_SL] + c1db[n];
        VCb[(size_t)(1024 << 10) + idx] = (bf16_t)s;
    } else {                 // sim for stacked cols 0..1023
        int s = bx - 1152;                  // 0..255
        int i = s >> 2, seg = s & 3;
        float* Gs  = (float*)smem;
        float* msk = Gs + 400;
        for (int q = tid; q < 400; q += 256) Gs[q] = GR[(size_t)i * 400 + q];
        if (tid < 20) msk[tid] = (wmask[i * 20 + tid] != 0) ? 1.f : 0.f;
        __syncthreads();
        sim_compute(i, seg * 256 + tid, CPat, VN, Gs, msk, SA);
    }
}

// ====== D8: c1d2/fc epi || attn cols 1024..1279 || rownorm rows 1024..1279 ====
__global__ __launch_bounds__(256) void d8_kernel(
    const float* __restrict__ CPc2, const float* __restrict__ CPfc,
    const float* __restrict__ c1db, const float* __restrict__ fcb,
    bf16_t* __restrict__ VCb, float* __restrict__ GV,
    const bf16_t* __restrict__ Wordsb, float* __restrict__ CPat,
    float* __restrict__ VN)
{
    __shared__ __align__(16) bf16_t smem[16384];
    bf16_t* sA = smem; bf16_t* sB = smem + 8192;
    int bx = blockIdx.x, tid = threadIdx.x;
    if (bx < 256) {
        int idx = bx * 256 + tid;           // < 65536
        int n = idx & 1023;
        float vc = c1db[n], gv = fcb[n];
        #pragma unroll
        for (int z = 0; z < 4; z++) {
            vc += CPc2[(size_t)z * CPC2_SL + idx];
            gv += CPfc[(size_t)z * CPFC_SL + idx];
        }
        VCb[(size_t)(1280 << 10) + idx] = (bf16_t)vc;
        GV[idx] = gv;
    } else if (bx < 416) {   // attn1: cols 1024..1279
        int g = bx - 256;                   // 0..159
        int z = g / 80, rem = g % 80;
        int xt = rem % 20, yt = rem / 20;   // yt 0..3
        gemm64(Wordsb, VCb, CPat + (size_t)z * CPAT_SL, 1344, 1024,
               xt * 64, 1024 + yt * 64, z * 512, 8, xt * 64, 1024 + yt * 64, sA, sB);
    } else {                 // rownorm rows 1024..1279
        int r = 1024 + (bx - 416) * 4 + (tid >> 6);
        rownorm_row(VCb, VN, r, tid);
    }
}

// = D9: attn cols 1280..1343 || rownorm rows 1280.. || gscore || sim cols 1024..1279
__global__ __launch_bounds__(256) void d9_kernel(
    const bf16_t* __restrict__ Wordsb, const bf16_t* __restrict__ VCb,
    float* __restrict__ CPat, float* __restrict__ VN,
    const float* __restrict__ sent, const float* __restrict__ GV,
    float* __restrict__ GS, const float* __restrict__ GR,
    const int* __restrict__ wmask, float* __restrict__ SA)
{
    __shared__ __align__(16) bf16_t smem[16384];
    bf16_t* sA = smem; bf16_t* sB = smem + 8192;
    int bx = blockIdx.x, tid = threadIdx.x;
    if (bx < 40) {           // attn2
        int z = bx / 20, xt = bx % 20;
        gemm64(Wordsb, VCb, CPat + (size_t)z * CPAT_SL, 1344, 1024,
               xt * 64, 1280, z * 512, 8, xt * 64, 1280, sA, sB);
    } else if (bx < 56) {    // rownorm rows 1280..1343
        int r = 1280 + (bx - 40) * 4 + (tid >> 6);
        rownorm_row(VCb, VN, r, tid);
    } else if (bx < 1080) {  // gscore (cosine of sentences vs GV)
        int item = (bx - 56) * 4 + (tid >> 6);
        int i = item >> 6, j = item & 63;
        int lane = tid & 63;
        const float* a = sent + (size_t)i * 1024;
        const float* b = GV + (size_t)j * 1024;
        float sab = 0.f, saa = 0.f, sbb = 0.f;
        #pragma unroll
        for (int q = 0; q < 16; q++) {
            int d = lane + 64 * q;
            float av = a[d], bv = b[d];
            sab += av * bv; saa += av * av; sbb += bv * bv;
        }
        #pragma unroll
        for (int o = 32; o; o >>= 1) {
            sab += __shfl_xor(sab, o, 64);
            saa += __shfl_xor(saa, o, 64);
            sbb += __shfl_xor(sbb, o, 64);
        }
        if (lane == 0)
            GS[item] = sab / (fmaxf(sqrtf(saa), 1e-8f) * fmaxf(sqrtf(sbb), 1e-8f));
    } else {                 // sim cols 1024..1279
        int i = bx - 1080;
        float* Gs  = (float*)smem;
        float* msk = Gs + 400;
        for (int q = tid; q < 400; q += 256) Gs[q] = GR[(size_t)i * 400 + q];
        if (tid < 20) msk[tid] = (wmask[i * 20 + tid] != 0) ? 1.f : 0.f;
        __syncthreads();
        sim_compute(i, 1024 + tid, CPat, VN, Gs, msk, SA);
    }
}

// ================= D10: sim cols 1280..1343 ===================================
__global__ __launch_bounds__(256) void d10_kernel(
    const float* __restrict__ CPat, const float* __restrict__ GR,
    const float* __restrict__ VN, const int* __restrict__ wmask,
    float* __restrict__ SA)
{
    __shared__ float Gs[400];
    __shared__ float msk[20];
    int i = blockIdx.x, tid = threadIdx.x;
    for (int q = tid; q < 400; q += 256) Gs[q] = GR[(size_t)i * 400 + q];
    if (tid < 20) msk[tid] = (wmask[i * 20 + tid] != 0) ? 1.f : 0.f;
    __syncthreads();
    if (tid < 64) sim_compute(i, 1280 + tid, CPat, VN, Gs, msk, SA);
}

// ================= D11: scores + positive_map =================================
__global__ __launch_bounds__(256) void d11_kernel(
    const float* __restrict__ SA, float* __restrict__ SC, float* __restrict__ out)
{
    int idx = blockIdx.x * 256 + threadIdx.x;   // 4096
    int i = idx >> 6, j = idx & 63;
    const float* row = SA + (size_t)idx * 21;
    float s = 0.f;
    #pragma unroll
    for (int t = 0; t < 21; t++) s += row[t];
    SC[idx] = s * (1.0f / 21.0f);
    if (i == j) {
        #pragma unroll
        for (int t = 0; t < 21; t++) out[1 + i * 21 + t] = row[t];
    }
}

// ================= D12: margin ranking loss ===================================
__global__ __launch_bounds__(256) void loss_kernel(
    const float* __restrict__ SC_, const float* __restrict__ GS_,
    float* __restrict__ out)
{
    __shared__ float d1[64], d2[64], red[4];
    int tid = threadIdx.x;
    if (tid < 64) { d1[tid] = SC_[tid * 65]; d2[tid] = GS_[tid * 65]; }
    __syncthreads();
    float acc = 0.f;
    for (int idx = tid; idx < 4096; idx += 256) {
        int i = idx >> 6, j = idx & 63;
        if (i != j) {
            float s = SC_[idx];
            acc += fmaxf(0.2f + s - d1[i], 0.f) + fmaxf(0.2f + s - d1[j], 0.f);
            float g = GS_[idx];
            acc += fmaxf(0.2f + g - d2[i], 0.f) + fmaxf(0.2f + g - d2[j], 0.f);
        }
    }
    #pragma unroll
    for (int o = 32; o; o >>= 1) acc += __shfl_xor(acc, o, 64);
    if ((tid & 63) == 0) red[tid >> 6] = acc;
    __syncthreads();
    if (tid == 0) out[0] = (red[0] + red[1] + red[2] + red[3]) * (1.0f / 64.0f);
}

// ------------------------------------------------------------------------------
extern "C" void kernel_launch(void* const* d_in, const int* in_sizes, int n_in,
                              void* d_out, int out_size, void* d_ws, size_t ws_size,
                              hipStream_t stream)
{
    const float* video     = (const float*)d_in[0];
    const float* words     = (const float*)d_in[1];
    const int*   w_masks   = (const int*)  d_in[2];
    const float* sentences = (const float*)d_in[3];
    const float* conv0_w   = (const float*)d_in[4];
    const float* conv0_b   = (const float*)d_in[5];
    const float* conv1_w   = (const float*)d_in[6];
    const float* conv1_b   = (const float*)d_in[7];
    const float* conv2_w   = (const float*)d_in[8];
    const float* conv2_b   = (const float*)d_in[9];
    const float* conv1d_w  = (const float*)d_in[10];
    const float* conv1d_b  = (const float*)d_in[11];
    const float* fc_w      = (const float*)d_in[12];
    const float* fc_b      = (const float*)d_in[13];
    float* out = (float*)d_out;
    float* ws = (float*)d_ws;

    // ---- flat workspace (float units) ----------------------------------------
    bf16_t* WT0    = (bf16_t*)(ws + 0);            // 1024x4096 bf16
    bf16_t* WT1    = (bf16_t*)(ws + 2097152);
    bf16_t* WT2    = (bf16_t*)(ws + 4194304);
    bf16_t* Vb     = (bf16_t*)(ws + 6291456);      // 4,194,304 bf16
    bf16_t* Wordsb = (bf16_t*)(ws + 8388608);      // 1,310,720 bf16
    bf16_t* C1b    = (bf16_t*)(ws + 9043968);      // 1,048,576 bf16
    bf16_t* Fb     = (bf16_t*)(ws + 9568256);      // 1,048,576 bf16
    bf16_t* Astack = (bf16_t*)(ws + 10092544);     // 1344x1024 bf16
    bf16_t* VCb    = (bf16_t*)(ws + 10780672);     // 1344x1024 bf16 (STACKED)
    float*  CP0    = ws + 11468800;                // 8 x 1,048,576 f
    float*  CP1    = ws + 19857408;                // 8 x 262,144 f
    float*  CPc0   = ws + 21954560;                // 2 x 1,048,576 f
    float*  CP2    = ws + 24051712;                // 8 x 65,536 f
    float*  CPc1   = ws + 24576000;                // 2 x 262,144 f
    float*  CPc2   = ws + 25100288;                // 4 x 65,536 f
    float*  CPfc   = ws + 25362432;                // 4 x 65,536 f
    float*  CPat   = ws + 25624576;                // 2 x 1,720,320 f
    float*  VN     = ws + 29065216;                // 1,344
    float*  GR     = ws + 29066560;                // 25,600
    float*  SA     = ws + 29092160;                // 86,016
    float*  SC     = ws + 29178176;                // 4,096
    float*  GV     = ws + 29182272;                // 65,536
    float*  GS     = ws + 29247808;                // 4,096 (ends 29,251,904)

    bf16_t* A2b = Astack + 1048576;   // conv1 output rows (b*4+t')

    dim3 blk(256);

    // D1: WT0 transpose + video cast (only what conv0 needs)
    prep0_kernel<<<8192, blk, 0, stream>>>(conv0_w, WT0, video, Vb);
    // D2: conv0 (128^2 tile, splitK x8) || WT1/WT2 transposes + remaining casts
    d2_kernel<<<12032, blk, 0, stream>>>(Vb, WT0, CP0, conv1_w, conv2_w, WT1, WT2,
                                         words, Wordsb, conv1d_w, C1b, fc_w, Fb);
    // D3: conv0 epilogue || word gram
    d3_kernel<<<10496, blk, 0, stream>>>(CP0, conv0_b, Astack, Wordsb, GR);
    // D4: conv1 || conv1d on conv0 rows
    d4_kernel<<<1024, blk, 0, stream>>>(Astack, WT1, C1b, CP1, CPc0);
    // D5: both epilogues
    d5_kernel<<<5120, blk, 0, stream>>>(CP1, conv1_b, A2b, CPc0, conv1d_b, VCb);
    // D6: conv2 || conv1d on conv1 rows || attn cols<1024 || rownorm rows<1024
    d6_kernel<<<1152, blk, 0, stream>>>(A2b, WT2, C1b, Wordsb, VCb, CP2, CPc1, CPat, VN);
    // D7: c1d2+fc (fused conv2-epilogue) || c1d1 epi || sim cols<1024
    d7_kernel<<<1408, blk, 0, stream>>>(CP2, conv2_b, C1b, Fb, CPc2, CPfc,
                                        CPc1, conv1d_b, VCb, CPat, GR, VN, w_masks, SA);
    // D8: c1d2/fc epi || attn cols 1024..1279 || rownorm rows 1024..1279
    d8_kernel<<<480, blk, 0, stream>>>(CPc2, CPfc, conv1d_b, fc_b, VCb, GV,
                                       Wordsb, CPat, VN);
    // D9: attn cols 1280.. || rownorm 1280.. || gscore || sim cols 1024..1279
    d9_kernel<<<1144, blk, 0, stream>>>(Wordsb, VCb, CPat, VN, sentences, GV, GS,
                                        GR, w_masks, SA);
    // D10-D12: sim tail, scores+posmap, loss
    d10_kernel<<<64, blk, 0, stream>>>(CPat, GR, VN, w_masks, SA);
    d11_kernel<<<16, blk, 0, stream>>>(SA, SC, out);
    loss_kernel<<<1, blk, 0, stream>>>(SC, GS, out);
}